// Round 2
// baseline (168481.934 us; speedup 1.0000x reference)
//
#include <hip/hip_runtime.h>

#define Hs 2048
#define Os 1024
#define NB 256
#define NT 512

typedef unsigned int   uint32;
typedef unsigned short ushort_t;

__device__ __forceinline__ float bf_lo(uint32 u) { return __uint_as_float(u << 16); }
__device__ __forceinline__ float bf_hi(uint32 u) { return __uint_as_float(u & 0xffff0000u); }

__device__ __forceinline__ void unp8(uint4 u, float* f) {
    f[0] = bf_lo(u.x); f[1] = bf_hi(u.x);
    f[2] = bf_lo(u.y); f[3] = bf_hi(u.y);
    f[4] = bf_lo(u.z); f[5] = bf_hi(u.z);
    f[6] = bf_lo(u.w); f[7] = bf_hi(u.w);
}

__device__ __forceinline__ ushort_t f2bf(float f) {
    uint32 u = __float_as_uint(f);
    u += 0x7fffu + ((u >> 16) & 1u);   // RNE
    return (ushort_t)(u >> 16);
}

__device__ __forceinline__ float fma8(const float* wf, const float* vf, float acc) {
#pragma unroll
    for (int k = 0; k < 8; ++k) acc = fmaf(wf[k], vf[k], acc);
    return acc;
}

__device__ __forceinline__ float dot4(float4 w, float4 v, float acc) {
    acc = fmaf(w.x, v.x, acc); acc = fmaf(w.y, v.y, acc);
    acc = fmaf(w.z, v.z, acc); acc = fmaf(w.w, v.w, acc);
    return acc;
}

// LDS swizzle for h_lds: swap 16B units across 128B blocks so the 32B-stride
// float4 read pattern covers all 8 bank groups per instruction.
__device__ __forceinline__ int sj(int j) { return j ^ (((j >> 5) & 1) << 2); }

// fast monotonic grid barrier: one atomic per block, acquire-spin on counter
__device__ __forceinline__ void gridbar(uint32* cnt, uint32 target) {
    __threadfence();            // release: make this block's writes device-visible
    __syncthreads();
    if (threadIdx.x == 0) {
        __hip_atomic_fetch_add(cnt, 1u, __ATOMIC_RELEASE, __HIP_MEMORY_SCOPE_AGENT);
        while (__hip_atomic_load(cnt, __ATOMIC_ACQUIRE, __HIP_MEMORY_SCOPE_AGENT) < target) {
            __builtin_amdgcn_s_sleep(1);
        }
    }
    __syncthreads();
    __threadfence();            // acquire: invalidate stale local cache lines
}

// ---- prep: f32 -> bf16 (as ushort) ----
__global__ void cvt_kernel(const float* __restrict__ src, ushort_t* __restrict__ dst, int n4) {
    int stride = gridDim.x * blockDim.x;
    for (int idx = blockIdx.x * blockDim.x + threadIdx.x; idx < n4; idx += stride) {
        float4 f = ((const float4*)src)[idx];
        ushort4 o;
        o.x = f2bf(f.x); o.y = f2bf(f.y); o.z = f2bf(f.z); o.w = f2bf(f.w);
        ((ushort4*)dst)[idx] = o;
    }
}

// ---- persistent cooperative decode kernel ----
__global__ void __launch_bounds__(NT) decode_kernel(
    const float* __restrict__ a,
    const float* __restrict__ encWih,
    const float* __restrict__ encBih,
    const float* __restrict__ encBhh,
    const float* __restrict__ intoW,
    const float* __restrict__ intoB,
    const float* __restrict__ decBih,
    const float* __restrict__ decBhh,
    const float* __restrict__ outB,
    const ushort_t* __restrict__ Wih,   // bf16 [3H][H]
    const ushort_t* __restrict__ Whh,   // bf16 [3H][H]
    const ushort_t* __restrict__ Wout,  // bf16 [O][H]
    float* __restrict__ hbuf,           // [2][H]
    float2* __restrict__ partials,      // [NB]
    uint32* __restrict__ barcnt,        // [1], memset to 0 per call
    float* __restrict__ out)            // [O]
{
    const int tid  = threadIdx.x;
    const int b    = blockIdx.x;
    const int lane = tid & 63;
    const int w    = tid >> 6;
    const int i    = b * 8 + w;   // this wave's h element (0..2047)

    __shared__ __align__(16) float    h_lds[Hs];
    __shared__ __align__(16) ushort_t v_lds[Hs];
    __shared__ float red_a[8], red_b[8];

    uint32 nbar = 0;   // barrier instance counter (monotonic target = nbar*NB)

    // hoisted loop invariants
    const float bxr = decBih[i], bxz = decBih[i + Hs], bxn = decBih[i + 2 * Hs];
    const float bhr = decBhh[i], bhz = decBhh[i + Hs], bhn = decBhh[i + 2 * Hs];
    const float iw0 = intoW[tid], iw1 = intoW[tid + 512], iw2 = intoW[tid + 1024], iw3 = intoW[tid + 1536];
    const float ib0 = intoB[tid], ib1 = intoB[tid + 512], ib2 = intoB[tid + 1024], ib3 = intoB[tid + 1536];
    const float ob0 = outB[b * 4 + 0], ob1 = outB[b * 4 + 1], ob2 = outB[b * 4 + 2], ob3 = outB[b * 4 + 3];

    const ushort_t* Xr = Wih + (size_t)i * Hs;
    const ushort_t* Xz = Wih + (size_t)(i + Hs) * Hs;
    const ushort_t* Xn = Wih + (size_t)(i + 2 * Hs) * Hs;
    const ushort_t* Hr = Whh + (size_t)i * Hs;
    const ushort_t* Hz = Whh + (size_t)(i + Hs) * Hs;
    const ushort_t* Hn = Whh + (size_t)(i + 2 * Hs) * Hs;

    // ===== encoder: h0 = GRUcell(a, h=0)  (gh = enc_bhh since Whh@0 = 0) =====
    for (int k = tid; k < Hs; k += NT) h_lds[sj(k)] = a[k];
    __syncthreads();
    {
        float sr = 0.f, sz = 0.f, sn = 0.f;
        const float* Rr = encWih + (size_t)i * Hs;
        const float* Rz = encWih + (size_t)(i + Hs) * Hs;
        const float* Rn = encWih + (size_t)(i + 2 * Hs) * Hs;
#pragma unroll
        for (int it = 0; it < 4; ++it) {
            int j0 = it * 512 + lane * 8;
            float4 a0 = *(const float4*)(h_lds + sj(j0));
            float4 a1 = *(const float4*)(h_lds + sj(j0 + 4));
            sr = dot4(*(const float4*)(Rr + j0), a0, sr);
            sr = dot4(*(const float4*)(Rr + j0 + 4), a1, sr);
            sz = dot4(*(const float4*)(Rz + j0), a0, sz);
            sz = dot4(*(const float4*)(Rz + j0 + 4), a1, sz);
            sn = dot4(*(const float4*)(Rn + j0), a0, sn);
            sn = dot4(*(const float4*)(Rn + j0 + 4), a1, sn);
        }
#pragma unroll
        for (int m = 1; m < 64; m <<= 1) {
            sr += __shfl_xor(sr, m, 64);
            sz += __shfl_xor(sz, m, 64);
            sn += __shfl_xor(sn, m, 64);
        }
        float gxr = sr + encBih[i];
        float gxz = sz + encBih[i + Hs];
        float gxn = sn + encBih[i + 2 * Hs];
        float ghr = encBhh[i], ghz = encBhh[i + Hs], ghn = encBhh[i + 2 * Hs];
        float r = 1.f / (1.f + __expf(-(gxr + ghr)));
        float z = 1.f / (1.f + __expf(-(gxz + ghz)));
        float n = tanhf(gxn + r * ghn);
        if (lane == 0) hbuf[i] = (1.f - z) * n;
    }
    gridbar(barcnt, ++nbar * NB);

    float x = 0.f;   // initial decoder input
    for (int t = 0; t < Os; ++t) {
        const int p = t & 1;
        const float* hprev = hbuf + p * Hs;
        float*       hnext = hbuf + (p ^ 1) * Hs;

        // [A] v = LeakyReLU(intoW*x + intoB) -> LDS(bf16); hprev -> LDS(f32, swizzled)
        {
            float v0 = fmaf(iw0, x, ib0); v0 = (v0 > 0.f) ? v0 : 0.01f * v0;
            float v1 = fmaf(iw1, x, ib1); v1 = (v1 > 0.f) ? v1 : 0.01f * v1;
            float v2 = fmaf(iw2, x, ib2); v2 = (v2 > 0.f) ? v2 : 0.01f * v2;
            float v3 = fmaf(iw3, x, ib3); v3 = (v3 > 0.f) ? v3 : 0.01f * v3;
            v_lds[tid]        = f2bf(v0);
            v_lds[tid + 512]  = f2bf(v1);
            v_lds[tid + 1024] = f2bf(v2);
            v_lds[tid + 1536] = f2bf(v3);
            h_lds[sj(tid)]        = hprev[tid];
            h_lds[sj(tid + 512)]  = hprev[tid + 512];
            h_lds[sj(tid + 1024)] = hprev[tid + 1024];
            h_lds[sj(tid + 1536)] = hprev[tid + 1536];
        }
        __syncthreads();

        // phase 1: GRU cell -> hnext[i]   (6 row-dots of 2048 per wave)
        {
            float axr = 0.f, axz = 0.f, axn = 0.f, ahr = 0.f, ahz = 0.f, ahn = 0.f;
#pragma unroll
            for (int it = 0; it < 4; ++it) {
                int j0 = it * 512 + lane * 8;
                float vf[8], hf[8], wf[8];
                unp8(*(const uint4*)(v_lds + j0), vf);
                *(float4*)(hf)     = *(const float4*)(h_lds + sj(j0));
                *(float4*)(hf + 4) = *(const float4*)(h_lds + sj(j0 + 4));
                unp8(*(const uint4*)(Xr + j0), wf); axr = fma8(wf, vf, axr);
                unp8(*(const uint4*)(Xz + j0), wf); axz = fma8(wf, vf, axz);
                unp8(*(const uint4*)(Xn + j0), wf); axn = fma8(wf, vf, axn);
                unp8(*(const uint4*)(Hr + j0), wf); ahr = fma8(wf, hf, ahr);
                unp8(*(const uint4*)(Hz + j0), wf); ahz = fma8(wf, hf, ahz);
                unp8(*(const uint4*)(Hn + j0), wf); ahn = fma8(wf, hf, ahn);
            }
#pragma unroll
            for (int m = 1; m < 64; m <<= 1) {
                axr += __shfl_xor(axr, m, 64); axz += __shfl_xor(axz, m, 64); axn += __shfl_xor(axn, m, 64);
                ahr += __shfl_xor(ahr, m, 64); ahz += __shfl_xor(ahz, m, 64); ahn += __shfl_xor(ahn, m, 64);
            }
            float r = 1.f / (1.f + __expf(-(axr + bxr + ahr + bhr)));
            float z = 1.f / (1.f + __expf(-(axz + bxz + ahz + bhz)));
            float n = tanhf(axn + bxn + r * (ahn + bhn));
            float hn = (1.f - z) * n + z * h_lds[sj(i)];
            if (lane == 0) hnext[i] = hn;
        }
        gridbar(barcnt, ++nbar * NB);   // B1: h_t visible

        // [B] logits: block b -> rows b*4..b*4+3 ; wave w -> row b*4+(w>>1), half (w&1)
        {
            const int row = b * 4 + (w >> 1);
            const int jb  = (w & 1) * 1024;
            const ushort_t* R  = Wout + (size_t)row * Hs + jb;
            const float*    hp = hnext + jb;
            float acc = 0.f;
#pragma unroll
            for (int it = 0; it < 2; ++it) {
                int j0 = it * 512 + lane * 8;
                float wf[8], hf[8];
                unp8(*(const uint4*)(R + j0), wf);
                *(float4*)(hf)     = *(const float4*)(hp + j0);
                *(float4*)(hf + 4) = *(const float4*)(hp + j0 + 4);
                acc = fma8(wf, hf, acc);
            }
#pragma unroll
            for (int m = 1; m < 64; m <<= 1) acc += __shfl_xor(acc, m, 64);
            if (lane == 0) red_a[w] = acc;
            __syncthreads();
            if (tid == 0) {
                float l0 = red_a[0] + red_a[1] + ob0;
                float l1 = red_a[2] + red_a[3] + ob1;
                float l2 = red_a[4] + red_a[5] + ob2;
                float l3 = red_a[6] + red_a[7] + ob3;
                float m = fmaxf(fmaxf(l0, l1), fmaxf(l2, l3));
                float s = __expf(l0 - m) + __expf(l1 - m) + __expf(l2 - m) + __expf(l3 - m);
                partials[b] = make_float2(m, s);
            }
        }
        gridbar(barcnt, ++nbar * NB);   // B2: partials visible

        // [C] reduce 256 partials -> topv (redundant, identical in every block)
        {
            float m = -1e30f, s = 0.f;
            if (tid < NB) { float2 P = partials[tid]; m = P.x; s = P.y; }
#pragma unroll
            for (int k = 1; k < 64; k <<= 1) {
                float mo = __shfl_xor(m, k, 64);
                float so = __shfl_xor(s, k, 64);
                float M = fmaxf(m, mo);
                s = s * __expf(m - M) + so * __expf(mo - M);
                m = M;
            }
            if (lane == 0) { red_a[w] = m; red_b[w] = s; }
            __syncthreads();
            float M = red_a[0], S = red_b[0];
#pragma unroll
            for (int q = 1; q < 8; ++q) {
                float mo = red_a[q], so = red_b[q];
                float Mn = fmaxf(M, mo);
                S = S * __expf(M - Mn) + so * __expf(mo - Mn);
                M = Mn;
            }
            x = -__logf(S);           // topv = max(l) - logsumexp(l) = -log(sum exp(l - max))
            if (b == 0 && tid == 0) out[t] = x;
        }
    }
}

extern "C" void kernel_launch(void* const* d_in, const int* in_sizes, int n_in,
                              void* d_out, int out_size, void* d_ws, size_t ws_size,
                              hipStream_t stream) {
    const float* a      = (const float*)d_in[0];
    const float* encWih = (const float*)d_in[1];
    // d_in[2] enc_Whh is unused (h0 = 0)
    const float* encBih = (const float*)d_in[3];
    const float* encBhh = (const float*)d_in[4];
    const float* intoW  = (const float*)d_in[5];
    const float* intoB  = (const float*)d_in[6];
    const float* decWih = (const float*)d_in[7];
    const float* decWhh = (const float*)d_in[8];
    const float* decBih = (const float*)d_in[9];
    const float* decBhh = (const float*)d_in[10];
    const float* outW   = (const float*)d_in[11];
    const float* outB   = (const float*)d_in[12];

    ushort_t* wsWih  = (ushort_t*)d_ws;
    ushort_t* wsWhh  = wsWih + (size_t)3 * Hs * Hs;
    ushort_t* wsWout = wsWhh + (size_t)3 * Hs * Hs;
    float*    hbuf   = (float*)(wsWout + (size_t)Os * Hs);
    float2*   parts  = (float2*)(hbuf + 2 * Hs);
    uint32*   barcnt = (uint32*)(parts + NB);
    float*    out    = (float*)d_out;

    cvt_kernel<<<4096, 256, 0, stream>>>(decWih, wsWih, 3 * Hs * Hs / 4);
    cvt_kernel<<<4096, 256, 0, stream>>>(decWhh, wsWhh, 3 * Hs * Hs / 4);
    cvt_kernel<<<1024, 256, 0, stream>>>(outW,  wsWout, Os * Hs / 4);
    hipMemsetAsync(barcnt, 0, sizeof(uint32), stream);

    void* args[] = {
        (void*)&a, (void*)&encWih, (void*)&encBih, (void*)&encBhh,
        (void*)&intoW, (void*)&intoB, (void*)&decBih, (void*)&decBhh,
        (void*)&outB, (void*)&wsWih, (void*)&wsWhh, (void*)&wsWout,
        (void*)&hbuf, (void*)&parts, (void*)&barcnt, (void*)&out
    };
    hipLaunchCooperativeKernel(reinterpret_cast<void*>(decode_kernel),
                               dim3(NB), dim3(NT), args, 0, stream);
}

// Round 3
// 11160.651 us; speedup vs baseline: 15.0961x; 15.0961x over previous
//
#include <hip/hip_runtime.h>

#define Hs 2048
#define Os 1024
#define NB 256
#define NT 512

typedef unsigned int       uint32;
typedef unsigned long long uint64;
typedef unsigned short     ushort_t;

__device__ __forceinline__ float bf_lo(uint32 u) { return __uint_as_float(u << 16); }
__device__ __forceinline__ float bf_hi(uint32 u) { return __uint_as_float(u & 0xffff0000u); }

__device__ __forceinline__ void unp8(uint4 u, float* f) {
    f[0] = bf_lo(u.x); f[1] = bf_hi(u.x);
    f[2] = bf_lo(u.y); f[3] = bf_hi(u.y);
    f[4] = bf_lo(u.z); f[5] = bf_hi(u.z);
    f[6] = bf_lo(u.w); f[7] = bf_hi(u.w);
}

__device__ __forceinline__ ushort_t f2bf(float f) {
    uint32 u = __float_as_uint(f);
    u += 0x7fffu + ((u >> 16) & 1u);   // RNE
    return (ushort_t)(u >> 16);
}

__device__ __forceinline__ float fma8(const float* wf, const float* vf, float acc) {
#pragma unroll
    for (int k = 0; k < 8; ++k) acc = fmaf(wf[k], vf[k], acc);
    return acc;
}

__device__ __forceinline__ float dot4(float4 w, float4 v, float acc) {
    acc = fmaf(w.x, v.x, acc); acc = fmaf(w.y, v.y, acc);
    acc = fmaf(w.z, v.z, acc); acc = fmaf(w.w, v.w, acc);
    return acc;
}

// LDS swizzle: swap 16B units across 128B blocks (bank-conflict fix, kept from R1)
__device__ __forceinline__ int sj(int j) { return j ^ (((j >> 5) & 1) << 2); }

// ---- MALL-coherent (L2-bypass, no cache maintenance) accessors ----
__device__ __forceinline__ uint32 gload(const uint32* p) {
    return __hip_atomic_load(p, __ATOMIC_RELAXED, __HIP_MEMORY_SCOPE_AGENT);
}
__device__ __forceinline__ void gstore(uint32* p, uint32 v) {
    __hip_atomic_store(p, v, __ATOMIC_RELAXED, __HIP_MEMORY_SCOPE_AGENT);
}
__device__ __forceinline__ uint64 gload64(const uint64* p) {
    return __hip_atomic_load(p, __ATOMIC_RELAXED, __HIP_MEMORY_SCOPE_AGENT);
}
__device__ __forceinline__ void gstore64(uint64* p, uint64 v) {
    __hip_atomic_store(p, v, __ATOMIC_RELAXED, __HIP_MEMORY_SCOPE_AGENT);
}

// ---- two-level tree barrier: 8 groups x 32 blocks, monotonic epochs ----
// bstate layout (uint32, 64-dword = 256B padded lines):
//   [g*64]        group arrival counters (g = 0..7)
//   [8*64]        root counter
//   [(9+g)*64]    go words
__device__ __forceinline__ void gridbar(uint32* bstate, uint32 epoch, int b) {
    // drain this wave's coherent stores so they're at MALL before arrival
    asm volatile("s_waitcnt vmcnt(0)" ::: "memory");
    __syncthreads();
    if (threadIdx.x == 0) {
        const int g = b & 7;
        uint32* grp  = bstate + g * 64;
        uint32* root = bstate + 8 * 64;
        uint32* go   = bstate + (9 + g) * 64;
        uint32 old = __hip_atomic_fetch_add(grp, 1u, __ATOMIC_RELAXED, __HIP_MEMORY_SCOPE_AGENT);
        if (old == epoch * 32u - 1u) {   // last arrival in group
            uint32 r = __hip_atomic_fetch_add(root, 1u, __ATOMIC_RELAXED, __HIP_MEMORY_SCOPE_AGENT);
            if (r == epoch * 8u - 1u) {  // last group: release everyone
#pragma unroll
                for (int k = 0; k < 8; ++k)
                    gstore(bstate + (9 + k) * 64, epoch);
            }
        }
        while (gload(go) < epoch) __builtin_amdgcn_s_sleep(1);
    }
    __syncthreads();
    asm volatile("" ::: "memory");
}

// ---- prep: f32 -> bf16 (as ushort) ----
__global__ void cvt_kernel(const float* __restrict__ src, ushort_t* __restrict__ dst, int n4) {
    int stride = gridDim.x * blockDim.x;
    for (int idx = blockIdx.x * blockDim.x + threadIdx.x; idx < n4; idx += stride) {
        float4 f = ((const float4*)src)[idx];
        ushort4 o;
        o.x = f2bf(f.x); o.y = f2bf(f.y); o.z = f2bf(f.z); o.w = f2bf(f.w);
        ((ushort4*)dst)[idx] = o;
    }
}

// ---- persistent cooperative decode kernel ----
__global__ void __launch_bounds__(NT) decode_kernel(
    const float* __restrict__ a,
    const float* __restrict__ encWih,
    const float* __restrict__ encBih,
    const float* __restrict__ encBhh,
    const float* __restrict__ intoW,
    const float* __restrict__ intoB,
    const float* __restrict__ decBih,
    const float* __restrict__ decBhh,
    const float* __restrict__ outB,
    const ushort_t* __restrict__ Wih,   // bf16 [3H][H]
    const ushort_t* __restrict__ Whh,   // bf16 [3H][H]
    const ushort_t* __restrict__ Wout,  // bf16 [O][H]
    float* __restrict__ hbuf,           // [H] broadcast buffer (single)
    float2* __restrict__ partials,      // [NB]
    uint32* __restrict__ bstate,        // barrier state, memset 0 per call
    float* __restrict__ out)            // [O]
{
    const int tid  = threadIdx.x;
    const int b    = blockIdx.x;
    const int lane = tid & 63;
    const int w    = tid >> 6;
    const int i    = b * 8 + w;   // this wave's h element (0..2047)

    uint32* hbu = (uint32*)hbuf;

    __shared__ __align__(16) float    h_lds[Hs];
    __shared__ __align__(16) ushort_t v_lds[Hs];
    __shared__ float red_a[8], red_b[8];

    uint32 nbar = 0;

    // hoisted loop invariants
    const float bxr = decBih[i], bxz = decBih[i + Hs], bxn = decBih[i + 2 * Hs];
    const float bhr = decBhh[i], bhz = decBhh[i + Hs], bhn = decBhh[i + 2 * Hs];
    const float iw0 = intoW[tid], iw1 = intoW[tid + 512], iw2 = intoW[tid + 1024], iw3 = intoW[tid + 1536];
    const float ib0 = intoB[tid], ib1 = intoB[tid + 512], ib2 = intoB[tid + 1024], ib3 = intoB[tid + 1536];
    const float ob0 = outB[b * 4 + 0], ob1 = outB[b * 4 + 1], ob2 = outB[b * 4 + 2], ob3 = outB[b * 4 + 3];

    const ushort_t* Xr = Wih + (size_t)i * Hs;
    const ushort_t* Xz = Wih + (size_t)(i + Hs) * Hs;
    const ushort_t* Xn = Wih + (size_t)(i + 2 * Hs) * Hs;
    const ushort_t* Hr = Whh + (size_t)i * Hs;
    const ushort_t* Hz = Whh + (size_t)(i + Hs) * Hs;
    const ushort_t* Hn = Whh + (size_t)(i + 2 * Hs) * Hs;

    // ===== encoder: h0 = GRUcell(a, h=0)  (gh = enc_bhh since Whh@0 = 0) =====
    for (int k = tid; k < Hs; k += NT) h_lds[sj(k)] = a[k];
    __syncthreads();
    {
        float sr = 0.f, sz = 0.f, sn = 0.f;
        const float* Rr = encWih + (size_t)i * Hs;
        const float* Rz = encWih + (size_t)(i + Hs) * Hs;
        const float* Rn = encWih + (size_t)(i + 2 * Hs) * Hs;
#pragma unroll
        for (int it = 0; it < 4; ++it) {
            int j0 = it * 512 + lane * 8;
            float4 a0 = *(const float4*)(h_lds + sj(j0));
            float4 a1 = *(const float4*)(h_lds + sj(j0 + 4));
            sr = dot4(*(const float4*)(Rr + j0), a0, sr);
            sr = dot4(*(const float4*)(Rr + j0 + 4), a1, sr);
            sz = dot4(*(const float4*)(Rz + j0), a0, sz);
            sz = dot4(*(const float4*)(Rz + j0 + 4), a1, sz);
            sn = dot4(*(const float4*)(Rn + j0), a0, sn);
            sn = dot4(*(const float4*)(Rn + j0 + 4), a1, sn);
        }
#pragma unroll
        for (int m = 1; m < 64; m <<= 1) {
            sr += __shfl_xor(sr, m, 64);
            sz += __shfl_xor(sz, m, 64);
            sn += __shfl_xor(sn, m, 64);
        }
        float gxr = sr + encBih[i];
        float gxz = sz + encBih[i + Hs];
        float gxn = sn + encBih[i + 2 * Hs];
        float r = 1.f / (1.f + __expf(-(gxr + encBhh[i])));
        float z = 1.f / (1.f + __expf(-(gxz + encBhh[i + Hs])));
        float n = tanhf(gxn + r * encBhh[i + 2 * Hs]);
        if (lane == 0) gstore(hbu + i, __float_as_uint((1.f - z) * n));
    }
    gridbar(bstate, ++nbar, b);

    // copy h0 -> h_lds (coherent loads, swizzled LDS)
#pragma unroll
    for (int k = 0; k < 4; ++k)
        h_lds[sj(tid + k * 512)] = __uint_as_float(gload(hbu + tid + k * 512));
    __syncthreads();

    float x = 0.f;   // initial decoder input
    for (int t = 0; t < Os; ++t) {
        // [A] v = LeakyReLU(intoW*x + intoB) -> LDS(bf16)   (h_lds already = h_{t-1})
        {
            float v0 = fmaf(iw0, x, ib0); v0 = (v0 > 0.f) ? v0 : 0.01f * v0;
            float v1 = fmaf(iw1, x, ib1); v1 = (v1 > 0.f) ? v1 : 0.01f * v1;
            float v2 = fmaf(iw2, x, ib2); v2 = (v2 > 0.f) ? v2 : 0.01f * v2;
            float v3 = fmaf(iw3, x, ib3); v3 = (v3 > 0.f) ? v3 : 0.01f * v3;
            v_lds[tid]        = f2bf(v0);
            v_lds[tid + 512]  = f2bf(v1);
            v_lds[tid + 1024] = f2bf(v2);
            v_lds[tid + 1536] = f2bf(v3);
        }
        __syncthreads();

        // phase 1: GRU cell -> h_t[i]  (6 row-dots of 2048 per wave)
        {
            float axr = 0.f, axz = 0.f, axn = 0.f, ahr = 0.f, ahz = 0.f, ahn = 0.f;
#pragma unroll
            for (int it = 0; it < 4; ++it) {
                int j0 = it * 512 + lane * 8;
                float vf[8], hf[8], wf[8];
                unp8(*(const uint4*)(v_lds + j0), vf);
                *(float4*)(hf)     = *(const float4*)(h_lds + sj(j0));
                *(float4*)(hf + 4) = *(const float4*)(h_lds + sj(j0 + 4));
                unp8(*(const uint4*)(Xr + j0), wf); axr = fma8(wf, vf, axr);
                unp8(*(const uint4*)(Xz + j0), wf); axz = fma8(wf, vf, axz);
                unp8(*(const uint4*)(Xn + j0), wf); axn = fma8(wf, vf, axn);
                unp8(*(const uint4*)(Hr + j0), wf); ahr = fma8(wf, hf, ahr);
                unp8(*(const uint4*)(Hz + j0), wf); ahz = fma8(wf, hf, ahz);
                unp8(*(const uint4*)(Hn + j0), wf); ahn = fma8(wf, hf, ahn);
            }
#pragma unroll
            for (int m = 1; m < 64; m <<= 1) {
                axr += __shfl_xor(axr, m, 64); axz += __shfl_xor(axz, m, 64); axn += __shfl_xor(axn, m, 64);
                ahr += __shfl_xor(ahr, m, 64); ahz += __shfl_xor(ahz, m, 64); ahn += __shfl_xor(ahn, m, 64);
            }
            float r = 1.f / (1.f + __expf(-(axr + bxr + ahr + bhr)));
            float z = 1.f / (1.f + __expf(-(axz + bxz + ahz + bhz)));
            float n = tanhf(axn + bxn + r * (ahn + bhn));
            float hn = (1.f - z) * n + z * h_lds[sj(i)];
            if (lane == 0) gstore(hbu + i, __float_as_uint(hn));
        }
        gridbar(bstate, ++nbar, b);   // B1: h_t at MALL

        // copy h_t -> h_lds (serves logits now AND GRU next step)
#pragma unroll
        for (int k = 0; k < 4; ++k)
            h_lds[sj(tid + k * 512)] = __uint_as_float(gload(hbu + tid + k * 512));
        __syncthreads();

        // [B] logits: block b -> rows b*4..b*4+3 ; wave w -> row b*4+(w>>1), half (w&1)
        {
            const int row = b * 4 + (w >> 1);
            const int jb  = (w & 1) * 1024;
            const ushort_t* R = Wout + (size_t)row * Hs + jb;
            float acc = 0.f;
#pragma unroll
            for (int it = 0; it < 2; ++it) {
                int j0 = it * 512 + lane * 8;
                float wf[8], hf[8];
                unp8(*(const uint4*)(R + j0), wf);
                *(float4*)(hf)     = *(const float4*)(h_lds + sj(jb + j0));
                *(float4*)(hf + 4) = *(const float4*)(h_lds + sj(jb + j0 + 4));
                acc = fma8(wf, hf, acc);
            }
#pragma unroll
            for (int m = 1; m < 64; m <<= 1) acc += __shfl_xor(acc, m, 64);
            if (lane == 0) red_a[w] = acc;
            __syncthreads();
            if (tid == 0) {
                float l0 = red_a[0] + red_a[1] + ob0;
                float l1 = red_a[2] + red_a[3] + ob1;
                float l2 = red_a[4] + red_a[5] + ob2;
                float l3 = red_a[6] + red_a[7] + ob3;
                float m = fmaxf(fmaxf(l0, l1), fmaxf(l2, l3));
                float s = __expf(l0 - m) + __expf(l1 - m) + __expf(l2 - m) + __expf(l3 - m);
                uint64 pu = (uint64)__float_as_uint(m) | ((uint64)__float_as_uint(s) << 32);
                gstore64((uint64*)&partials[b], pu);
            }
        }
        gridbar(bstate, ++nbar, b);   // B2: partials at MALL

        // [C] reduce 256 partials -> topv (redundant, identical in every block)
        {
            float m = -1e30f, s = 0.f;
            if (tid < NB) {
                uint64 pu = gload64((const uint64*)&partials[tid]);
                m = __uint_as_float((uint32)pu);
                s = __uint_as_float((uint32)(pu >> 32));
            }
#pragma unroll
            for (int k = 1; k < 64; k <<= 1) {
                float mo = __shfl_xor(m, k, 64);
                float so = __shfl_xor(s, k, 64);
                float M = fmaxf(m, mo);
                s = s * __expf(m - M) + so * __expf(mo - M);
                m = M;
            }
            if (lane == 0) { red_a[w] = m; red_b[w] = s; }
            __syncthreads();
            float M = red_a[0], S = red_b[0];
#pragma unroll
            for (int q = 1; q < 8; ++q) {
                float mo = red_a[q], so = red_b[q];
                float Mn = fmaxf(M, mo);
                S = S * __expf(M - Mn) + so * __expf(mo - Mn);
                M = Mn;
            }
            x = -__logf(S);   // topv = max(l) - logsumexp(l)
            if (b == 0 && tid == 0) out[t] = x;
        }
    }
}

extern "C" void kernel_launch(void* const* d_in, const int* in_sizes, int n_in,
                              void* d_out, int out_size, void* d_ws, size_t ws_size,
                              hipStream_t stream) {
    const float* a      = (const float*)d_in[0];
    const float* encWih = (const float*)d_in[1];
    // d_in[2] enc_Whh unused (h0 = 0)
    const float* encBih = (const float*)d_in[3];
    const float* encBhh = (const float*)d_in[4];
    const float* intoW  = (const float*)d_in[5];
    const float* intoB  = (const float*)d_in[6];
    const float* decWih = (const float*)d_in[7];
    const float* decWhh = (const float*)d_in[8];
    const float* decBih = (const float*)d_in[9];
    const float* decBhh = (const float*)d_in[10];
    const float* outW   = (const float*)d_in[11];
    const float* outB   = (const float*)d_in[12];

    ushort_t* wsWih  = (ushort_t*)d_ws;
    ushort_t* wsWhh  = wsWih + (size_t)3 * Hs * Hs;
    ushort_t* wsWout = wsWhh + (size_t)3 * Hs * Hs;
    float*    hbuf   = (float*)(wsWout + (size_t)Os * Hs);
    float2*   parts  = (float2*)(hbuf + 2 * Hs);
    uint32*   bstate = (uint32*)(parts + NB);
    float*    out    = (float*)d_out;

    cvt_kernel<<<4096, 256, 0, stream>>>(decWih, wsWih, 3 * Hs * Hs / 4);
    cvt_kernel<<<4096, 256, 0, stream>>>(decWhh, wsWhh, 3 * Hs * Hs / 4);
    cvt_kernel<<<1024, 256, 0, stream>>>(outW,  wsWout, Os * Hs / 4);
    hipMemsetAsync(bstate, 0, 17 * 64 * sizeof(uint32), stream);

    void* args[] = {
        (void*)&a, (void*)&encWih, (void*)&encBih, (void*)&encBhh,
        (void*)&intoW, (void*)&intoB, (void*)&decBih, (void*)&decBhh,
        (void*)&outB, (void*)&wsWih, (void*)&wsWhh, (void*)&wsWout,
        (void*)&hbuf, (void*)&parts, (void*)&bstate, (void*)&out
    };
    hipLaunchCooperativeKernel(reinterpret_cast<void*>(decode_kernel),
                               dim3(NB), dim3(NT), args, 0, stream);
}